// Round 11
// baseline (50.848 us; speedup 1.0000x reference)
//
#include <hip/hip_runtime.h>
#include <math.h>

#define NN 4096
#define ROWS 16
#define HALF 8

typedef float fvec4 __attribute__((ext_vector_type(4)));

// out[b,u,v] = -sgn(u-v) * p[b,u] * p[b,v] * sin(2(u-v))   (Re of complex64
// ref; harness stores .astype(float32))
//   p[b,x] = sqrt(0.5) * sqrt(|V[b,x]| + 1e-10) / (1 + x)
// Identity: p_v*sin(2(u-v)) = su*cp[v] - cu*sp[v],
//   cp[v]=p_v*cos(2v), sp[v]=p_v*sin(2v).

// Kernel 1: exact-f64 table precompute into d_ws (cp|sp per batch, 2*NN each).
__global__ __launch_bounds__(256) void bs_tables(const float* __restrict__ V,
                                                 int nV,
                                                 float* __restrict__ ws) {
    const int i = blockIdx.x * 256 + threadIdx.x;    // i = b*NN + v
    if (i >= nV) return;
    const int b = i >> 12, v = i & (NN - 1);
    const float val = V[i];
    const float p = 0.70710678118654752f * sqrtf(fabsf(val) + 1e-10f)
                    / (1.0f + (float)v);
    const double a = 2.0 * (double)v;
    float* wb = ws + (size_t)b * (2 * NN);
    wb[v]      = p * (float)cos(a);
    wb[NN + v] = p * (float)sin(a);
}

// Kernel 2: stream kernel. R11 change: WAVE-CONTIGUOUS store runs — wave w
// owns the unbroken quarter-row [w*1024, (w+1)*1024) floats; its 4 sub-iters
// (fully unrolled) walk it in 1 KB steps, so each wave's store stream is a
// sequential 4 KB run per row (x2 rows via pairing). Lane stride stays 16 B
// (coalesced stores, conflict-free ds_read_b128).
__global__ __launch_bounds__(256) void bs_main(const float* __restrict__ V,
                                               int nV,
                                               const float* __restrict__ ws,
                                               int use_ws,
                                               float* __restrict__ out,
                                               int nrows) {
    __shared__ float tab[2 * NN];          // cp = tab[0..NN), sp = tab[NN..2NN)
    __shared__ float rs_c[ROWS], rs_s[ROWS];   // pu*cos(2u), pu*sin(2u)

    const int t = threadIdx.x;
    const int w = t >> 6;                  // wave 0..3
    const int lane = t & 63;
    const int row0 = blockIdx.x * ROWS;
    const int b = row0 >> 12;              // N == 4096
    const int vbase = b << 12;

    if (use_ws) {
        const fvec4* __restrict__ src = (const fvec4*)(ws + (size_t)b * (2 * NN));
        fvec4* __restrict__ dst = (fvec4*)tab;
        #pragma unroll
        for (int j = t; j < (2 * NN) / 4; j += 256) dst[j] = src[j];
    } else {                               // fallback: build tables in-kernel
        for (int i = t; i < NN; i += 256) {
            const int gi = vbase + i;
            const float val = (gi < nV) ? V[gi] : 0.0f;
            const float p = 0.70710678118654752f * sqrtf(fabsf(val) + 1e-10f)
                            / (1.0f + (float)i);
            const double a = 2.0 * (double)i;
            tab[i]      = p * (float)cos(a);
            tab[NN + i] = p * (float)sin(a);
        }
    }

    if (t < ROWS) {                        // per-row scalars, parallel
        const int u = (row0 + t) & (NN - 1);
        const int gu = vbase + u;
        const float vu = (gu < nV) ? V[gu] : 0.0f;
        const float pu = 0.70710678118654752f * sqrtf(fabsf(vu) + 1e-10f)
                         / (1.0f + (float)u);
        const double a = 2.0 * (double)u;
        rs_c[t] = pu * (float)cos(a);
        rs_s[t] = pu * (float)sin(a);
    }
    __syncthreads();

    const int vw = w * 1024 + lane * 4;    // wave-contiguous quarter-row base

    if (row0 + ROWS <= nrows) {
        // ---- fast path: all 16 rows in-bounds, zero per-iter branches ----
        for (int r = 0; r < HALF; ++r) {
            const int rowA = row0 + r;
            const int rowB = rowA + HALF;
            const int uA = rowA & (NN - 1);
            const int uB = rowB & (NN - 1);
            const float cA = rs_c[r],        sA = rs_s[r];
            const float cB = rs_c[r + HALF], sB = rs_s[r + HALF];
            float* __restrict__ orowA = out + (size_t)rowA * NN;
            float* __restrict__ orowB = out + (size_t)rowB * NN;

            #pragma unroll
            for (int i = 0; i < 4; ++i) {  // 4 x 1 KB steps within quarter-row
                const int v0 = vw + i * 256;
                const fvec4 cp4 = *(const fvec4*)&tab[v0];        // ds_read_b128
                const fvec4 sp4 = *(const fvec4*)&tab[NN + v0];   // ds_read_b128

                fvec4 oA, oB;
                #pragma unroll
                for (int k = 0; k < 4; ++k) {
                    const int v = v0 + k;
                    const float mA = sA * cp4[k] - cA * sp4[k];
                    const float mB = sB * cp4[k] - cB * sp4[k];
                    oA[k] = (uA > v) ? -mA : ((uA < v) ? mA : 0.0f);
                    oB[k] = (uB > v) ? -mB : ((uB < v) ? mB : 0.0f);
                }
                *(fvec4*)(orowA + v0) = oA;
                *(fvec4*)(orowB + v0) = oB;
            }
        }
    } else {
        // ---- guarded tail path (partial last block) ----
        for (int r = 0; r < ROWS; ++r) {
            const int row = row0 + r;
            if (row >= nrows) return;
            const int u = row & (NN - 1);
            const float cu = rs_c[r], su = rs_s[r];
            float* __restrict__ orow = out + (size_t)row * NN;
            #pragma unroll
            for (int i = 0; i < 4; ++i) {
                const int v0 = vw + i * 256;
                const fvec4 cp4 = *(const fvec4*)&tab[v0];
                const fvec4 sp4 = *(const fvec4*)&tab[NN + v0];
                fvec4 o;
                #pragma unroll
                for (int k = 0; k < 4; ++k) {
                    const int v = v0 + k;
                    const float m = su * cp4[k] - cu * sp4[k];
                    o[k] = (u > v) ? -m : ((u < v) ? m : 0.0f);
                }
                *(fvec4*)(orow + v0) = o;
            }
        }
    }
}

extern "C" void kernel_launch(void* const* d_in, const int* in_sizes, int n_in,
                              void* d_out, int out_size, void* d_ws, size_t ws_size,
                              hipStream_t stream) {
    const float* V = (const float*)d_in[0];
    const int nV = in_sizes[0];                       // B*N = 16384 expected

    long long nrows = (long long)out_size / NN;       // one float per (b,u,v)
    if (nrows <= 0) return;
    const int grid = (int)((nrows + ROWS - 1) / ROWS);

    const size_t ws_needed = (size_t)((nV + NN - 1) / NN) * (2 * NN) * sizeof(float);
    const int use_ws = (d_ws != nullptr && ws_size >= ws_needed) ? 1 : 0;

    if (use_ws) {
        bs_tables<<<(nV + 255) / 256, 256, 0, stream>>>(V, nV, (float*)d_ws);
    }
    bs_main<<<grid, 256, 0, stream>>>(V, nV, (const float*)d_ws, use_ws,
                                      (float*)d_out, (int)nrows);
}